// Round 4
// baseline (487.347 us; speedup 1.0000x reference)
//
#include <hip/hip_runtime.h>

// LatentLinearModel: out[i] = dot(U[users[i]], V[jokes[i]]) + a[users[i]] + b[jokes[i]] + g
// K=64 floats/row = 256 B contiguous.
//
// R3 analysis: MLP-insensitive at ~140us kernel time => random-gather DRAM
// efficiency wall (~2.1 TB/s effective), NOT latency. U footprint (256MB)
// thrashes L3 so the 37% duplicate gathers refetch. R4: bucket-sort rows by
// user index (4096 buckets ~ 256 U-rows each), process in sorted order:
// duplicates coalesce in L2, U stream gains DRAM page/TLB locality.
// Pipeline: zero -> hist(LDS) -> scan(1 blk) -> scatter -> compute(sorted).

constexpr int KV  = 16;    // float4s per 64-float row
constexpr int RPG = 4;     // rows per 16-lane group
constexpr int NB  = 4096;  // buckets

__global__ __launch_bounds__(256) void zero_kernel(unsigned* __restrict__ counts) {
    int i = blockIdx.x * blockDim.x + threadIdx.x;
    if (i < NB) counts[i] = 0u;
}

__global__ __launch_bounds__(256) void hist_kernel(const int* __restrict__ users,
                                                   unsigned* __restrict__ counts,
                                                   int B, int shift) {
    __shared__ unsigned h[NB];
    for (int j = threadIdx.x; j < NB; j += 256) h[j] = 0u;
    __syncthreads();
    for (int i = blockIdx.x * blockDim.x + threadIdx.x; i < B; i += gridDim.x * blockDim.x)
        atomicAdd(&h[((unsigned)users[i]) >> shift], 1u);
    __syncthreads();
    for (int j = threadIdx.x; j < NB; j += 256) {
        unsigned c = h[j];
        if (c) atomicAdd(&counts[j], c);
    }
}

// Exclusive scan of counts[NB] -> cursor[NB]. One block, 256 threads x 16.
__global__ __launch_bounds__(256) void scan_kernel(const unsigned* __restrict__ counts,
                                                   unsigned* __restrict__ cursor) {
    __shared__ unsigned psum[256];
    const int t = threadIdx.x;
    unsigned local[16];
    unsigned s = 0;
    for (int k = 0; k < 16; ++k) { local[k] = counts[t * 16 + k]; s += local[k]; }
    psum[t] = s;
    __syncthreads();
    for (int off = 1; off < 256; off <<= 1) {
        unsigned v = (t >= off) ? psum[t - off] : 0u;
        __syncthreads();
        psum[t] += v;
        __syncthreads();
    }
    unsigned base = (t == 0) ? 0u : psum[t - 1];
    for (int k = 0; k < 16; ++k) { cursor[t * 16 + k] = base; base += local[k]; }
}

__global__ __launch_bounds__(256) void scatter_kernel(const int* __restrict__ users,
                                                      unsigned* __restrict__ cursor,
                                                      unsigned* __restrict__ sortedUi,
                                                      unsigned* __restrict__ sortedRow,
                                                      int B, int shift) {
    for (int i = blockIdx.x * blockDim.x + threadIdx.x; i < B; i += gridDim.x * blockDim.x) {
        const unsigned ui = (unsigned)users[i];
        const unsigned pos = atomicAdd(&cursor[ui >> shift], 1u);
        sortedUi[pos]  = ui;
        sortedRow[pos] = (unsigned)i;
    }
}

__global__ __launch_bounds__(256) void compute_kernel(
    const unsigned* __restrict__ sortedUi,
    const unsigned* __restrict__ sortedRow,
    const int* __restrict__ jokes,
    const float* __restrict__ U,
    const float* __restrict__ V,
    const float* __restrict__ a,
    const float* __restrict__ b,
    const float* __restrict__ g,
    float* __restrict__ out,
    int B)
{
    const int sub = threadIdx.x & 15;
    const int grp = blockIdx.x * 16 + (threadIdx.x >> 4);
    const int ng  = B / RPG;

    const float4* __restrict__ U4 = reinterpret_cast<const float4*>(U);
    const float4* __restrict__ V4 = reinterpret_cast<const float4*>(V);
    const float g0 = g[0];

    if (grp < ng) {
        const uint4 su = reinterpret_cast<const uint4*>(sortedUi)[grp];
        const uint4 sr = reinterpret_cast<const uint4*>(sortedRow)[grp];
        const unsigned ui[RPG]   = {su.x, su.y, su.z, su.w};
        const unsigned orig[RPG] = {sr.x, sr.y, sr.z, sr.w};

        int ji[RPG];
#pragma unroll
        for (int r = 0; r < RPG; ++r) ji[r] = jokes[orig[r]];

        float4 uu[RPG], vv[RPG];
#pragma unroll
        for (int r = 0; r < RPG; ++r) {
            uu[r] = U4[(size_t)ui[r] * KV + sub];
            vv[r] = V4[(size_t)ji[r] * KV + sub];
        }

        float ab[RPG], bb[RPG];
#pragma unroll
        for (int r = 0; r < RPG; ++r) { ab[r] = a[ui[r]]; bb[r] = b[ji[r]]; }

#pragma unroll
        for (int r = 0; r < RPG; ++r) {
            float d = uu[r].x * vv[r].x + uu[r].y * vv[r].y
                    + uu[r].z * vv[r].z + uu[r].w * vv[r].w;
            d += __shfl_down(d, 8, 16);
            d += __shfl_down(d, 4, 16);
            d += __shfl_down(d, 2, 16);
            d += __shfl_down(d, 1, 16);
            if (sub == 0)
                out[orig[r]] = d + ab[r] + bb[r] + g0;
        }
    }

    // tail positions (none for B = 1<<20)
    if (blockIdx.x == 0 && threadIdx.x == 0) {
        for (int p = ng * RPG; p < B; ++p) {
            const unsigned ui = sortedUi[p];
            const unsigned orig = sortedRow[p];
            const int ji = jokes[orig];
            float d = 0.f;
            for (int k = 0; k < 64; ++k) d += U[(size_t)ui * 64 + k] * V[(size_t)ji * 64 + k];
            out[orig] = d + a[ui] + b[ji] + g0;
        }
    }
}

extern "C" void kernel_launch(void* const* d_in, const int* in_sizes, int n_in,
                              void* d_out, int out_size, void* d_ws, size_t ws_size,
                              hipStream_t stream)
{
    const int*   users = (const int*)d_in[0];
    const int*   jokes = (const int*)d_in[1];
    const float* U     = (const float*)d_in[2];
    const float* V     = (const float*)d_in[3];
    const float* a     = (const float*)d_in[4];
    const float* b     = (const float*)d_in[5];
    const float* g     = (const float*)d_in[6];
    float*       out   = (float*)d_out;

    const int B = in_sizes[0];          // 1048576 rows
    const int N = in_sizes[2] / 64;     // user-table rows

    // bucket shift: buckets of U-rows such that bucket count <= NB
    int shift = 0;
    while ((((long long)(N - 1)) >> shift) >= NB) ++shift;   // N=1e6 -> 8

    unsigned* wsu       = (unsigned*)d_ws;
    unsigned* counts    = wsu;             // [NB]
    unsigned* cursor    = wsu + NB;        // [NB]
    unsigned* sortedUi  = wsu + 2 * NB;    // [B]
    unsigned* sortedRow = sortedUi + B;    // [B]

    zero_kernel<<<(NB + 255) / 256, 256, 0, stream>>>(counts);
    hist_kernel<<<128, 256, 0, stream>>>(users, counts, B, shift);
    scan_kernel<<<1, 256, 0, stream>>>(counts, cursor);
    scatter_kernel<<<512, 256, 0, stream>>>(users, cursor, sortedUi, sortedRow, B, shift);

    const int ng = B / RPG;
    const int grid = (ng + 15) / 16;    // 16 groups (64 rows) per block
    compute_kernel<<<grid, 256, 0, stream>>>(sortedUi, sortedRow, jokes, U, V, a, b, g, out, B);
}

// Round 5
// 388.835 us; speedup vs baseline: 1.2534x; 1.2534x over previous
//
#include <hip/hip_runtime.h>

// LatentLinearModel: out[i] = dot(U[users[i]], V[jokes[i]]) + a[users[i]] + b[jokes[i]] + g
// K=64 floats/row = 256 B contiguous.
//
// R4 post-mortem: sort regressed (+100us overhead). dur_us tracks kernel time
// 1:1; R2 kernel ~135us vs ~55us floor. Theory: U's 256MB single-use gather
// stream thrashes V (26MB, 10x reuse) out of L3, so V's 256MB of requests
// refetch from HBM -> ~500MB total @ ~4TB/s = 135us. R5 = R2 structure +
// non-temporal (nt) hints on the single-use streams (U rows, indices, out)
// so V/a/b stay cache-resident.

constexpr int KV  = 16;   // float4s per 64-float row
constexpr int RPG = 4;    // rows per 16-lane group

typedef __attribute__((ext_vector_type(4))) float f4_t;
typedef __attribute__((ext_vector_type(4))) int   i4_t;

__global__ __launch_bounds__(256) void latent_linear_kernel(
    const int* __restrict__ users,
    const int* __restrict__ jokes,
    const float* __restrict__ U,
    const float* __restrict__ V,
    const float* __restrict__ a,
    const float* __restrict__ b,
    const float* __restrict__ g,
    float* __restrict__ out,
    int B)
{
    const int tid  = blockIdx.x * blockDim.x + threadIdx.x;
    const int grp  = tid >> 4;          // 16-lane group id
    const int sub  = tid & 15;          // which float4 of a row
    const int base = grp * RPG;
    if (base >= B) return;

    const f4_t* __restrict__ U4 = reinterpret_cast<const f4_t*>(U);
    const f4_t* __restrict__ V4 = reinterpret_cast<const f4_t*>(V);
    const i4_t* __restrict__ users4 = reinterpret_cast<const i4_t*>(users);
    const i4_t* __restrict__ jokes4 = reinterpret_cast<const i4_t*>(jokes);

    const float g0 = g[0];

    if (base + RPG <= B) {
        // index loads: single-use stream -> nt
        const i4_t u4 = __builtin_nontemporal_load(&users4[grp]);
        const i4_t j4 = __builtin_nontemporal_load(&jokes4[grp]);
        const int ui[RPG] = {u4.x, u4.y, u4.z, u4.w};
        const int ji[RPG] = {j4.x, j4.y, j4.z, j4.w};

        // U rows: ~single-use random stream, 256MB footprint -> nt so it
        // doesn't evict V from L2/L3. V rows: 26MB, 10x reuse -> cacheable.
        f4_t uu[RPG], vv[RPG];
#pragma unroll
        for (int r = 0; r < RPG; ++r) {
            uu[r] = __builtin_nontemporal_load(&U4[(size_t)ui[r] * KV + sub]);
            vv[r] = V4[(size_t)ji[r] * KV + sub];
        }

        // bias gathers: a (4MB) / b (0.4MB) tables, heavy line reuse -> cacheable
        float ab[RPG], bb[RPG];
#pragma unroll
        for (int r = 0; r < RPG; ++r) { ab[r] = a[ui[r]]; bb[r] = b[ji[r]]; }

#pragma unroll
        for (int r = 0; r < RPG; ++r) {
            float d = uu[r].x * vv[r].x + uu[r].y * vv[r].y
                    + uu[r].z * vv[r].z + uu[r].w * vv[r].w;
            d += __shfl_down(d, 8, 16);
            d += __shfl_down(d, 4, 16);
            d += __shfl_down(d, 2, 16);
            d += __shfl_down(d, 1, 16);
            if (sub == 0)
                __builtin_nontemporal_store(d + ab[r] + bb[r] + g0, &out[base + r]);
        }
    } else {
        // tail (not hit for B = 1<<20)
        for (int r = 0; r < RPG && base + r < B; ++r) {
            const int row = base + r;
            const int ui = users[row], ji = jokes[row];
            const f4_t uu = U4[(size_t)ui * KV + sub];
            const f4_t vv = V4[(size_t)ji * KV + sub];
            float d = uu.x * vv.x + uu.y * vv.y + uu.z * vv.z + uu.w * vv.w;
            d += __shfl_down(d, 8, 16);
            d += __shfl_down(d, 4, 16);
            d += __shfl_down(d, 2, 16);
            d += __shfl_down(d, 1, 16);
            if (sub == 0)
                out[row] = d + a[ui] + b[ji] + g0;
        }
    }
}

extern "C" void kernel_launch(void* const* d_in, const int* in_sizes, int n_in,
                              void* d_out, int out_size, void* d_ws, size_t ws_size,
                              hipStream_t stream)
{
    const int*   users = (const int*)d_in[0];
    const int*   jokes = (const int*)d_in[1];
    const float* U     = (const float*)d_in[2];
    const float* V     = (const float*)d_in[3];
    const float* a     = (const float*)d_in[4];
    const float* b     = (const float*)d_in[5];
    const float* g     = (const float*)d_in[6];
    float*       out   = (float*)d_out;

    const int B = in_sizes[0];              // 1048576 rows
    const int groups = (B + RPG - 1) / RPG;
    const long long threads_total = (long long)groups * 16;
    const int block = 256;
    const int grid = (int)((threads_total + block - 1) / block);

    latent_linear_kernel<<<grid, block, 0, stream>>>(users, jokes, U, V, a, b, g, out, B);
}